// Round 1
// baseline (61.667 us; speedup 1.0000x reference)
//
#include <hip/hip_runtime.h>
#include <hip/hip_bf16.h>

// AWQ 4-bit linear: out[32,11008] = x[32,4096] @ ((q - z) * s) + bias
// M=32, IN=4096, OUT=11008, G=128 (32 groups), qweight packed 8 cols/int32
// with nibble order REV=[0,4,1,5,2,6,3,7] (shift = 4*REV[col%8]).

#define IN_F   4096
#define OUT_F  11008
#define WCOLS  1376              // OUT_F / 8
#define KSPLIT 4
#define CHUNK  (IN_F / KSPLIT)   // 1024
#define KSTEPS (CHUNK / 32)      // 32
#define NBLK   688               // (OUT_F/16 tiles * KSPLIT) / 4 waves

typedef __attribute__((ext_vector_type(8))) short  short8;
typedef __attribute__((ext_vector_type(4))) float  f32x4;

__device__ __forceinline__ short f2bf(float f) {
  return (short)__builtin_bit_cast(unsigned short, (__bf16)f);
}

__global__ void awq_init(const float* __restrict__ bias, float* __restrict__ out) {
  int o = blockIdx.x * 256 + threadIdx.x;          // grid.x = 43 -> 11008 cols
  out[blockIdx.y * OUT_F + o] = bias[o];           // grid.y = 32 rows
}

__global__ __launch_bounds__(256) void awq_main(
    const float* __restrict__ x, const int* __restrict__ qw,
    const int* __restrict__ qz, const float* __restrict__ sc,
    float* __restrict__ out)
{
  const int tid  = threadIdx.x;
  const int wave = tid >> 6;
  const int lane = tid & 63;

  // Bijective XCD swizzle (688 = 8 * 86): contiguous logical blocks per XCD
  // so the 4 blocks sharing each 128B qweight line land on one XCD-L2.
  const int b  = blockIdx.x;
  const int L  = (b & 7) * (NBLK / 8) + (b >> 3);
  const int chunk = L / (NBLK / KSPLIT);   // 172 blocks per k-chunk
  const int tg    = L % (NBLK / KSPLIT);
  const int tile  = tg * 4 + wave;         // 16-column tile index, 0..687

  const int colt  = lane & 15;             // MFMA non-k lane index
  const int g4    = lane >> 4;             // k-quarter: k = 8*g4 + j
  const int col   = tile * 16 + colt;
  const int wc    = col >> 3;              // packed word column
  // shift = 4*REV[col&7], REV[i] = (i>>1) | ((i&1)<<2)
  const int shift = ((col & 6) << 1) | ((col & 1) << 4);

  const int kb    = chunk * CHUNK;
  int qidx  = (kb + 8 * g4) * WCOLS + wc;  // qweight element index
  int xidx  = colt * IN_F + kb + 8 * g4;   // x element index (row = colt)

  f32x4 acc0 = {0.f, 0.f, 0.f, 0.f};
  f32x4 acc1 = {0.f, 0.f, 0.f, 0.f};
  float s = 0.f, zs = 0.f;

  #pragma unroll 4
  for (int it = 0; it < KSTEPS; ++it) {
    if ((it & 3) == 0) {                   // new group every 128 k = 4 ksteps
      const int grp = (kb >> 7) + (it >> 2);
      const int z   = (qz[grp * WCOLS + wc] >> shift) & 0xF;
      s  = sc[grp * OUT_F + col];
      zs = -(float)z * s;                  // w = q*s + zs
    }

    // B fragment: 8 k-consecutive packed words, one nibble each (8 lanes
    // share each word -> coalescer merges; HBM fetch stays 22.5 MB).
    int q[8];
    #pragma unroll
    for (int j = 0; j < 8; ++j) q[j] = qw[qidx + j * WCOLS];
    qidx += 32 * WCOLS;

    short8 bf;
    #pragma unroll
    for (int j = 0; j < 8; ++j)
      bf[j] = f2bf(fmaf((float)((q[j] >> shift) & 0xF), s, zs));

    // A fragments: rows colt and colt+16, 8 consecutive fp32 each.
    const f32x4* xa0 = (const f32x4*)(x + xidx);
    const f32x4* xa1 = (const f32x4*)(x + xidx + 16 * IN_F);
    const f32x4 a0 = xa0[0], a1 = xa0[1];
    const f32x4 a2 = xa1[0], a3 = xa1[1];
    xidx += 32;

    short8 af0, af1;
    #pragma unroll
    for (int j = 0; j < 4; ++j) {
      af0[j]     = f2bf(a0[j]);
      af0[j + 4] = f2bf(a1[j]);
      af1[j]     = f2bf(a2[j]);
      af1[j + 4] = f2bf(a3[j]);
    }

    acc0 = __builtin_amdgcn_mfma_f32_16x16x32_bf16(af0, bf, acc0, 0, 0, 0);
    acc1 = __builtin_amdgcn_mfma_f32_16x16x32_bf16(af1, bf, acc1, 0, 0, 0);
  }

  // D layout: row = 4*g4 + i, col = lane&15. Accumulate k-split partials.
  const int r0 = 4 * g4;
  #pragma unroll
  for (int i = 0; i < 4; ++i) {
    atomicAdd(&out[(r0 + i) * OUT_F + col],      acc0[i]);
    atomicAdd(&out[(16 + r0 + i) * OUT_F + col], acc1[i]);
  }
}

extern "C" void kernel_launch(void* const* d_in, const int* in_sizes, int n_in,
                              void* d_out, int out_size, void* d_ws, size_t ws_size,
                              hipStream_t stream) {
  const float* x    = (const float*)d_in[0];
  const int*   qwp  = (const int*)d_in[1];
  const int*   qzp  = (const int*)d_in[2];
  const float* scp  = (const float*)d_in[3];
  const float* bias = (const float*)d_in[4];
  float* out = (float*)d_out;

  awq_init<<<dim3(43, 32), 256, 0, stream>>>(bias, out);
  awq_main<<<NBLK, 256, 0, stream>>>(x, qwp, qzp, scp, out);
}

// Round 4
// 39.279 us; speedup vs baseline: 1.5700x; 1.5700x over previous
//
#include <hip/hip_runtime.h>
#include <hip/hip_bf16.h>

// AWQ 4-bit linear: out[32,11008] = x[32,4096] @ ((q - z)*s) + bias
// Structure: BN=128 col-block, BK=32 k-tiles. Each thread loads 2 coalesced
// qweight dwords (word wr, k-rows 2kp/2kp+1), dequants 16 nibbles, writes
// k-pairs to LDS in [col][k] layout (col stride 16 dwords, k-pair index XOR-
// swizzled by 4*(wr&3)). B-fragment = one ds_read_b128 (k contiguous).
// Double-buffered, 1 barrier/tile. KSPLIT=16, fp32 atomics onto bias-init out.

#define IN_F   4096
#define OUT_F  11008
#define WCOLS  1376
#define NCOLB  86                 // 11008/128
#define KSPLIT 16
#define CHUNK  (IN_F/KSPLIT)      // 256
#define NTILE  (CHUNK/32)         // 8
#define NBLK   (NCOLB*KSPLIT)     // 1376

typedef __attribute__((ext_vector_type(8))) short  short8;
typedef __attribute__((ext_vector_type(4))) short  short4v;
typedef __attribute__((ext_vector_type(4))) float  f32x4;
typedef __attribute__((ext_vector_type(4))) int    int4v;

__device__ __forceinline__ short f2bf(float f) {
  return (short)__builtin_bit_cast(unsigned short, (__bf16)f);
}
__device__ __forceinline__ f32x4 mfma16(short8 a, short8 b, f32x4 c) {
  return __builtin_amdgcn_mfma_f32_16x16x32_bf16(a, b, c, 0, 0, 0);
}

__global__ void awq_init(const float* __restrict__ bias, float* __restrict__ out) {
  int o = blockIdx.x * 256 + threadIdx.x;          // 43*256 = 11008
  out[blockIdx.y * OUT_F + o] = bias[o];
}

__global__ void xconv(const float* __restrict__ x, unsigned short* __restrict__ xb) {
  int i = blockIdx.x * 256 + threadIdx.x;          // 128 blocks -> 32768 f32x4
  f32x4 v = ((const f32x4*)x)[i];
  short4v o;
  #pragma unroll
  for (int j = 0; j < 4; ++j) o[j] = f2bf(v[j]);
  ((short4v*)xb)[i] = o;
}

template<bool PRE>
__global__ __launch_bounds__(256, 4) void awq_main(
    const float* __restrict__ x, const unsigned short* __restrict__ xb,
    const int* __restrict__ qw, const int* __restrict__ qz,
    const float* __restrict__ sc, float* __restrict__ out)
{
  // [col 0..127][k-pair 0..15] dwords, double-buffered: 2 x 8KB.
  __shared__ int lds[2][2048];

  const int tid  = threadIdx.x;
  const int w    = tid >> 6;           // wave -> 32-col subtile
  const int lane = tid & 63;
  const int q4   = lane >> 4;

  // Bijective XCD swizzle (1376 = 8*172)
  const int b  = blockIdx.x;
  const int L  = (b & 7) * (NBLK / 8) + (b >> 3);
  const int colblk = L % NCOLB;
  const int kchunk = L / NCOLB;

  const int cb  = colblk * 128;        // first output column
  const int wcb = colblk * 16;         // first packed word
  const int K0  = kchunk * CHUNK;
  const int g0  = kchunk * (CHUNK / 128);

  const int wr = tid & 15;             // word within block -> cols 8wr..8wr+7
  const int kp = tid >> 4;             // k-pair 0..15 -> k = 2kp, 2kp+1

  float s8[8], zs8[8];
  auto load_group = [&](int g) {
    const f32x4 sa = *(const f32x4*)(sc + g * OUT_F + cb + 8 * wr);
    const f32x4 sb = *(const f32x4*)(sc + g * OUT_F + cb + 8 * wr + 4);
    const int   zw = qz[g * WCOLS + wcb + wr];
    #pragma unroll
    for (int j = 0; j < 8; ++j) {
      const int sh = 4 * (j >> 1) + 16 * (j & 1);   // shift = 4*REV[j]
      const float sv = (j < 4) ? sa[j] : sb[j - 4];
      s8[j]  = sv;
      zs8[j] = -(float)((zw >> sh) & 15) * sv;
    }
  };
  auto load_q = [&](int t, int& q0, int& q1) {
    const int r = (K0 + t * 32 + 2 * kp) * WCOLS + wcb + wr;
    q0 = qw[r];
    q1 = qw[r + WCOLS];
  };
  auto load_a = [&](int t, int mf) -> short8 {
    const int m = (lane & 15) + 16 * mf;
    const int k = K0 + t * 32 + q4 * 8;
    if constexpr (PRE) {
      return *(const short8*)(xb + m * IN_F + k);
    } else {
      const f32x4* xp = (const f32x4*)(x + m * IN_F + k);
      f32x4 lo = xp[0], hi = xp[1];
      short8 af;
      #pragma unroll
      for (int j = 0; j < 4; ++j) { af[j] = f2bf(lo[j]); af[4 + j] = f2bf(hi[j]); }
      return af;
    }
  };
  auto read_b = [&](int p, int c) -> short8 {
    const int idx = c * 16 + 4 * (q4 ^ ((c >> 3) & 3));   // 16B-aligned
    return __builtin_bit_cast(short8, *(const int4v*)&lds[p][idx]);
  };

  // ---- prologue
  load_group(g0);
  int q0c, q1c; load_q(0, q0c, q1c);
  short8 a0c = load_a(0, 0), a1c = load_a(0, 1);
  f32x4 acc[2][2] = {};

  #pragma unroll
  for (int t = 0; t < NTILE; ++t) {
    int q0n = 0, q1n = 0;
    short8 a0n = {}, a1n = {};
    if (t + 1 < NTILE) {                 // prefetch next tile (overlaps barrier+MFMA)
      load_q(t + 1, q0n, q1n);
      a0n = load_a(t + 1, 0);
      a1n = load_a(t + 1, 1);
    }
    if (t == 4) load_group(g0 + 1);      // tiles 4..7 use the second group

    // dequant 16 nibbles -> 8 packed bf16x2 -> LDS [col][k] (swizzled k-pair)
    const int p = t & 1;
    const int kps = kp ^ ((wr & 3) << 2);
    #pragma unroll
    for (int j = 0; j < 8; ++j) {
      const int sh = 4 * (j >> 1) + 16 * (j & 1);
      const float lo = fmaf((float)((q0c >> sh) & 15), s8[j], zs8[j]);
      const float hi = fmaf((float)((q1c >> sh) & 15), s8[j], zs8[j]);
      const unsigned int pk =
          (unsigned int)(unsigned short)__builtin_bit_cast(unsigned short, (__bf16)lo) |
          ((unsigned int)(unsigned short)__builtin_bit_cast(unsigned short, (__bf16)hi) << 16);
      lds[p][(8 * wr + j) * 16 + kps] = (int)pk;
    }
    __syncthreads();

    const int c0 = w * 32 + (lane & 15);
    short8 bf0 = read_b(p, c0);
    short8 bf1 = read_b(p, c0 + 16);

    acc[0][0] = mfma16(a0c, bf0, acc[0][0]);
    acc[0][1] = mfma16(a0c, bf1, acc[0][1]);
    acc[1][0] = mfma16(a1c, bf0, acc[1][0]);
    acc[1][1] = mfma16(a1c, bf1, acc[1][1]);

    q0c = q0n; q1c = q1n; a0c = a0n; a1c = a1n;
  }

  // ---- epilogue: k-split partials via fp32 atomics (out pre-set to bias)
  const int col0 = cb + w * 32 + (lane & 15);
  const int r0 = q4 * 4;
  #pragma unroll
  for (int mf = 0; mf < 2; ++mf) {
    #pragma unroll
    for (int i = 0; i < 4; ++i) {
      const int row = mf * 16 + r0 + i;
      atomicAdd(out + row * OUT_F + col0,      acc[mf][0][i]);
      atomicAdd(out + row * OUT_F + col0 + 16, acc[mf][1][i]);
    }
  }
}

extern "C" void kernel_launch(void* const* d_in, const int* in_sizes, int n_in,
                              void* d_out, int out_size, void* d_ws, size_t ws_size,
                              hipStream_t stream) {
  const float* x    = (const float*)d_in[0];
  const int*   qwp  = (const int*)d_in[1];
  const int*   qzp  = (const int*)d_in[2];
  const float* scp  = (const float*)d_in[3];
  const float* bias = (const float*)d_in[4];
  float* out = (float*)d_out;

  awq_init<<<dim3(43, 32), 256, 0, stream>>>(bias, out);

  const bool pre = ws_size >= (size_t)(32 * 4096 * 2);
  if (pre) {
    unsigned short* xb = (unsigned short*)d_ws;
    xconv<<<128, 256, 0, stream>>>(x, xb);
    awq_main<true><<<NBLK, 256, 0, stream>>>(x, xb, qwp, qzp, scp, out);
  } else {
    awq_main<false><<<NBLK, 256, 0, stream>>>(x, nullptr, qwp, qzp, scp, out);
  }
}

// Round 5
// 32.878 us; speedup vs baseline: 1.8756x; 1.1947x over previous
//
#include <hip/hip_runtime.h>
#include <hip/hip_bf16.h>

// AWQ 4-bit linear: out[32,11008] = x[32,4096] @ ((q - z)*s) + bias
// BN=128 col-block, BK=32 k-tiles, dequant->LDS [col][k] (XOR-swizzled
// k-pair), B-fragment = ds_read_b128, double-buffered, 1 barrier/tile.
// KSPLIT=16; partials go to private ws slabs (plain stores), awq_reduce
// sums slabs + bias. No atomics in the hot path.

#define IN_F   4096
#define OUT_F  11008
#define WCOLS  1376
#define NCOLB  86                 // 11008/128
#define KSPLIT 16
#define CHUNK  (IN_F/KSPLIT)      // 256
#define NTILE  (CHUNK/32)         // 8
#define NBLK   (NCOLB*KSPLIT)     // 1376
#define MROWS  32
#define SLAB   (MROWS*OUT_F)      // floats per k-partial slab (352256)

typedef __attribute__((ext_vector_type(8))) short  short8;
typedef __attribute__((ext_vector_type(4))) short  short4v;
typedef __attribute__((ext_vector_type(4))) float  f32x4;
typedef __attribute__((ext_vector_type(4))) int    int4v;

__device__ __forceinline__ short f2bf(float f) {
  return (short)__builtin_bit_cast(unsigned short, (__bf16)f);
}
__device__ __forceinline__ f32x4 mfma16(short8 a, short8 b, f32x4 c) {
  return __builtin_amdgcn_mfma_f32_16x16x32_bf16(a, b, c, 0, 0, 0);
}

__global__ void awq_init(const float* __restrict__ bias, float* __restrict__ out) {
  int o = blockIdx.x * 256 + threadIdx.x;
  out[blockIdx.y * OUT_F + o] = bias[o];
}

__global__ void xconv(const float* __restrict__ x, unsigned short* __restrict__ xb) {
  int i = blockIdx.x * 256 + threadIdx.x;          // 128 blocks -> 32768 f32x4
  f32x4 v = ((const f32x4*)x)[i];
  short4v o;
  #pragma unroll
  for (int j = 0; j < 4; ++j) o[j] = f2bf(v[j]);
  ((short4v*)xb)[i] = o;
}

__global__ __launch_bounds__(256) void awq_reduce(
    const float* __restrict__ ws, const float* __restrict__ bias,
    float* __restrict__ out)
{
  const int i = blockIdx.x * 256 + threadIdx.x;    // f32x4 id, 88064 total
  const f32x4* w4 = (const f32x4*)ws;
  f32x4 s = w4[i];
  #pragma unroll
  for (int k = 1; k < KSPLIT; ++k) s += w4[k * (SLAB / 4) + i];
  const f32x4 b = *(const f32x4*)(bias + (i % (OUT_F / 4)) * 4);
  ((f32x4*)out)[i] = s + b;
}

template<bool PRE, bool TOWS>
__global__ __launch_bounds__(256, 4) void awq_main(
    const float* __restrict__ x, const unsigned short* __restrict__ xb,
    const int* __restrict__ qw, const int* __restrict__ qz,
    const float* __restrict__ sc, float* __restrict__ outp)
{
  // [col 0..127][k-pair 0..15] dwords, double-buffered: 2 x 8KB.
  __shared__ int lds[2][2048];

  const int tid  = threadIdx.x;
  const int w    = tid >> 6;           // wave -> 32-col subtile
  const int lane = tid & 63;
  const int q4   = lane >> 4;

  // Bijective XCD swizzle (1376 = 8*172)
  const int b  = blockIdx.x;
  const int L  = (b & 7) * (NBLK / 8) + (b >> 3);
  const int colblk = L % NCOLB;
  const int kchunk = L / NCOLB;

  const int cb  = colblk * 128;        // first output column
  const int wcb = colblk * 16;         // first packed word
  const int K0  = kchunk * CHUNK;
  const int g0  = kchunk * (CHUNK / 128);

  const int wr = tid & 15;             // word within block -> cols 8wr..8wr+7
  const int kp = tid >> 4;             // k-pair 0..15 -> k = 2kp, 2kp+1

  float s8[8], zs8[8];
  auto load_group = [&](int g) {
    const f32x4 sa = *(const f32x4*)(sc + g * OUT_F + cb + 8 * wr);
    const f32x4 sb = *(const f32x4*)(sc + g * OUT_F + cb + 8 * wr + 4);
    const int   zw = qz[g * WCOLS + wcb + wr];
    #pragma unroll
    for (int j = 0; j < 8; ++j) {
      const int sh = 4 * (j >> 1) + 16 * (j & 1);   // shift = 4*REV[j]
      const float sv = (j < 4) ? sa[j] : sb[j - 4];
      s8[j]  = sv;
      zs8[j] = -(float)((zw >> sh) & 15) * sv;
    }
  };
  auto load_q = [&](int t, int& q0, int& q1) {
    const int r = (K0 + t * 32 + 2 * kp) * WCOLS + wcb + wr;
    q0 = qw[r];
    q1 = qw[r + WCOLS];
  };
  auto load_a = [&](int t, int mf) -> short8 {
    const int m = (lane & 15) + 16 * mf;
    const int k = K0 + t * 32 + q4 * 8;
    if constexpr (PRE) {
      return *(const short8*)(xb + m * IN_F + k);
    } else {
      const f32x4* xp = (const f32x4*)(x + m * IN_F + k);
      f32x4 lo = xp[0], hi = xp[1];
      short8 af;
      #pragma unroll
      for (int j = 0; j < 4; ++j) { af[j] = f2bf(lo[j]); af[4 + j] = f2bf(hi[j]); }
      return af;
    }
  };
  auto read_b = [&](int p, int c) -> short8 {
    const int idx = c * 16 + 4 * (q4 ^ ((c >> 3) & 3));   // 16B-aligned
    return __builtin_bit_cast(short8, *(const int4v*)&lds[p][idx]);
  };

  // ---- prologue
  load_group(g0);
  int q0c, q1c; load_q(0, q0c, q1c);
  f32x4 acc[2][2] = {};

  #pragma unroll
  for (int t = 0; t < NTILE; ++t) {
    // A-fragments issued early; dequant VALU hides their (L1/L2-hot) latency.
    short8 a0 = load_a(t, 0), a1 = load_a(t, 1);
    int q0n = 0, q1n = 0;
    if (t + 1 < NTILE) load_q(t + 1, q0n, q1n);   // prefetch next q tile
    if (t == 4) load_group(g0 + 1);               // tiles 4..7: second group

    // dequant 16 nibbles -> 8 packed bf16x2 -> LDS [col][k] (swizzled k-pair)
    const int p = t & 1;
    const int kps = kp ^ ((wr & 3) << 2);
    #pragma unroll
    for (int j = 0; j < 8; ++j) {
      const int sh = 4 * (j >> 1) + 16 * (j & 1);
      const float lo = fmaf((float)((q0c >> sh) & 15), s8[j], zs8[j]);
      const float hi = fmaf((float)((q1c >> sh) & 15), s8[j], zs8[j]);
      const unsigned int pk =
          (unsigned int)(unsigned short)__builtin_bit_cast(unsigned short, (__bf16)lo) |
          ((unsigned int)(unsigned short)__builtin_bit_cast(unsigned short, (__bf16)hi) << 16);
      lds[p][(8 * wr + j) * 16 + kps] = (int)pk;
    }
    __syncthreads();

    const int c0 = w * 32 + (lane & 15);
    short8 bf0 = read_b(p, c0);
    short8 bf1 = read_b(p, c0 + 16);

    acc[0][0] = mfma16(a0, bf0, acc[0][0]);
    acc[0][1] = mfma16(a0, bf1, acc[0][1]);
    acc[1][0] = mfma16(a1, bf0, acc[1][0]);
    acc[1][1] = mfma16(a1, bf1, acc[1][1]);

    q0c = q0n; q1c = q1n;
  }

  // ---- epilogue
  const int col0 = cb + w * 32 + (lane & 15);
  const int r0 = q4 * 4;
  if constexpr (TOWS) {
    // plain stores to this k-chunk's private partial slab
    float* wsp = outp + kchunk * SLAB;
    #pragma unroll
    for (int mf = 0; mf < 2; ++mf) {
      #pragma unroll
      for (int i = 0; i < 4; ++i) {
        const int row = mf * 16 + r0 + i;
        wsp[row * OUT_F + col0]      = acc[mf][0][i];
        wsp[row * OUT_F + col0 + 16] = acc[mf][1][i];
      }
    }
  } else {
    // fallback: fp32 atomics onto bias-initialized out
    #pragma unroll
    for (int mf = 0; mf < 2; ++mf) {
      #pragma unroll
      for (int i = 0; i < 4; ++i) {
        const int row = mf * 16 + r0 + i;
        atomicAdd(outp + row * OUT_F + col0,      acc[mf][0][i]);
        atomicAdd(outp + row * OUT_F + col0 + 16, acc[mf][1][i]);
      }
    }
  }
}

extern "C" void kernel_launch(void* const* d_in, const int* in_sizes, int n_in,
                              void* d_out, int out_size, void* d_ws, size_t ws_size,
                              hipStream_t stream) {
  const float* x    = (const float*)d_in[0];
  const int*   qwp  = (const int*)d_in[1];
  const int*   qzp  = (const int*)d_in[2];
  const float* scp  = (const float*)d_in[3];
  const float* bias = (const float*)d_in[4];
  float* out = (float*)d_out;

  const size_t ws_part = (size_t)KSPLIT * SLAB * sizeof(float);   // 22.5 MB
  const size_t xb_sz   = (size_t)MROWS * IN_F * 2;                // 256 KB

  if (ws_size >= ws_part + xb_sz) {
    float* ws = (float*)d_ws;
    unsigned short* xb = (unsigned short*)((char*)d_ws + ws_part);
    xconv<<<128, 256, 0, stream>>>(x, xb);
    awq_main<true, true><<<NBLK, 256, 0, stream>>>(x, xb, qwp, qzp, scp, ws);
    awq_reduce<<<SLAB / 4 / 256, 256, 0, stream>>>(ws, bias, out);
  } else {
    awq_init<<<dim3(43, 32), 256, 0, stream>>>(bias, out);
    awq_main<false, false><<<NBLK, 256, 0, stream>>>(x, nullptr, qwp, qzp, scp, out);
  }
}

// Round 6
// 32.410 us; speedup vs baseline: 1.9027x; 1.0144x over previous
//
#include <hip/hip_runtime.h>
#include <hip/hip_bf16.h>

// AWQ 4-bit linear: out[32,11008] = x[32,4096] @ ((q - z)*s) + bias
// BN=128 col-block, BK=32 k-tiles, dequant->LDS [col][k] (XOR-swizzled
// k-pair), B-fragment = ds_read_b128, double-buffered, 1 barrier/tile.
// KSPLIT=16; partials go to private ws slabs (plain stores), awq_reduce
// sums slabs + bias. No atomics in the hot path.
// Round 6: #pragma unroll 2 on the tile loop (was full unroll) to bound
// compiler load-hoisting -> keep VGPR under the launch_bounds(256,4) cap
// of 128 and avoid scratch spills.

#define IN_F   4096
#define OUT_F  11008
#define WCOLS  1376
#define NCOLB  86                 // 11008/128
#define KSPLIT 16
#define CHUNK  (IN_F/KSPLIT)      // 256
#define NTILE  (CHUNK/32)         // 8
#define NBLK   (NCOLB*KSPLIT)     // 1376
#define MROWS  32
#define SLAB   (MROWS*OUT_F)      // floats per k-partial slab (352256)

typedef __attribute__((ext_vector_type(8))) short  short8;
typedef __attribute__((ext_vector_type(4))) short  short4v;
typedef __attribute__((ext_vector_type(4))) float  f32x4;
typedef __attribute__((ext_vector_type(4))) int    int4v;

__device__ __forceinline__ short f2bf(float f) {
  return (short)__builtin_bit_cast(unsigned short, (__bf16)f);
}
__device__ __forceinline__ f32x4 mfma16(short8 a, short8 b, f32x4 c) {
  return __builtin_amdgcn_mfma_f32_16x16x32_bf16(a, b, c, 0, 0, 0);
}

__global__ void awq_init(const float* __restrict__ bias, float* __restrict__ out) {
  int o = blockIdx.x * 256 + threadIdx.x;
  out[blockIdx.y * OUT_F + o] = bias[o];
}

__global__ void xconv(const float* __restrict__ x, unsigned short* __restrict__ xb) {
  int i = blockIdx.x * 256 + threadIdx.x;          // 128 blocks -> 32768 f32x4
  f32x4 v = ((const f32x4*)x)[i];
  short4v o;
  #pragma unroll
  for (int j = 0; j < 4; ++j) o[j] = f2bf(v[j]);
  ((short4v*)xb)[i] = o;
}

__global__ __launch_bounds__(256) void awq_reduce(
    const float* __restrict__ ws, const float* __restrict__ bias,
    float* __restrict__ out)
{
  const int i = blockIdx.x * 256 + threadIdx.x;    // f32x4 id, 88064 total
  const f32x4* w4 = (const f32x4*)ws;
  f32x4 s = w4[i];
  #pragma unroll
  for (int k = 1; k < KSPLIT; ++k) s += w4[k * (SLAB / 4) + i];
  const f32x4 b = *(const f32x4*)(bias + (i % (OUT_F / 4)) * 4);
  ((f32x4*)out)[i] = s + b;
}

template<bool PRE, bool TOWS>
__global__ __launch_bounds__(256, 4) void awq_main(
    const float* __restrict__ x, const unsigned short* __restrict__ xb,
    const int* __restrict__ qw, const int* __restrict__ qz,
    const float* __restrict__ sc, float* __restrict__ outp)
{
  // [col 0..127][k-pair 0..15] dwords, double-buffered: 2 x 8KB.
  __shared__ int lds[2][2048];

  const int tid  = threadIdx.x;
  const int w    = tid >> 6;           // wave -> 32-col subtile
  const int lane = tid & 63;
  const int q4   = lane >> 4;

  // Bijective XCD swizzle (1376 = 8*172)
  const int b  = blockIdx.x;
  const int L  = (b & 7) * (NBLK / 8) + (b >> 3);
  const int colblk = L % NCOLB;
  const int kchunk = L / NCOLB;

  const int cb  = colblk * 128;        // first output column
  const int wcb = colblk * 16;         // first packed word
  const int K0  = kchunk * CHUNK;
  const int g0  = kchunk * (CHUNK / 128);

  const int wr = tid & 15;             // word within block -> cols 8wr..8wr+7
  const int kp = tid >> 4;             // k-pair 0..15 -> k = 2kp, 2kp+1

  float s8[8], zs8[8];
  auto load_group = [&](int g) {
    const f32x4 sa = *(const f32x4*)(sc + g * OUT_F + cb + 8 * wr);
    const f32x4 sb = *(const f32x4*)(sc + g * OUT_F + cb + 8 * wr + 4);
    const int   zw = qz[g * WCOLS + wcb + wr];
    #pragma unroll
    for (int j = 0; j < 8; ++j) {
      const int sh = 4 * (j >> 1) + 16 * (j & 1);   // shift = 4*REV[j]
      const float sv = (j < 4) ? sa[j] : sb[j - 4];
      s8[j]  = sv;
      zs8[j] = -(float)((zw >> sh) & 15) * sv;
    }
  };
  auto load_q = [&](int t, int& q0, int& q1) {
    const int r = (K0 + t * 32 + 2 * kp) * WCOLS + wcb + wr;
    q0 = qw[r];
    q1 = qw[r + WCOLS];
  };
  auto load_a = [&](int t, int mf) -> short8 {
    const int m = (lane & 15) + 16 * mf;
    const int k = K0 + t * 32 + q4 * 8;
    if constexpr (PRE) {
      return *(const short8*)(xb + m * IN_F + k);
    } else {
      const f32x4* xp = (const f32x4*)(x + m * IN_F + k);
      f32x4 lo = xp[0], hi = xp[1];
      short8 af;
      #pragma unroll
      for (int j = 0; j < 4; ++j) { af[j] = f2bf(lo[j]); af[4 + j] = f2bf(hi[j]); }
      return af;
    }
  };
  auto read_b = [&](int p, int c) -> short8 {
    const int idx = c * 16 + 4 * (q4 ^ ((c >> 3) & 3));   // 16B-aligned
    return __builtin_bit_cast(short8, *(const int4v*)&lds[p][idx]);
  };

  // ---- prologue
  load_group(g0);
  int q0c, q1c; load_q(0, q0c, q1c);
  f32x4 acc[2][2] = {};

  #pragma unroll 2
  for (int t = 0; t < NTILE; ++t) {
    // A-fragments issued early; dequant VALU hides their (L1/L2-hot) latency.
    short8 a0 = load_a(t, 0), a1 = load_a(t, 1);
    int q0n = 0, q1n = 0;
    if (t + 1 < NTILE) load_q(t + 1, q0n, q1n);   // prefetch next q tile
    if (t == 4) load_group(g0 + 1);               // tiles 4..7: second group

    // dequant 16 nibbles -> 8 packed bf16x2 -> LDS [col][k] (swizzled k-pair)
    const int p = t & 1;
    const int kps = kp ^ ((wr & 3) << 2);
    #pragma unroll
    for (int j = 0; j < 8; ++j) {
      const int sh = 4 * (j >> 1) + 16 * (j & 1);
      const float lo = fmaf((float)((q0c >> sh) & 15), s8[j], zs8[j]);
      const float hi = fmaf((float)((q1c >> sh) & 15), s8[j], zs8[j]);
      const unsigned int pk =
          (unsigned int)(unsigned short)__builtin_bit_cast(unsigned short, (__bf16)lo) |
          ((unsigned int)(unsigned short)__builtin_bit_cast(unsigned short, (__bf16)hi) << 16);
      lds[p][(8 * wr + j) * 16 + kps] = (int)pk;
    }
    __syncthreads();

    const int c0 = w * 32 + (lane & 15);
    short8 bf0 = read_b(p, c0);
    short8 bf1 = read_b(p, c0 + 16);

    acc[0][0] = mfma16(a0, bf0, acc[0][0]);
    acc[0][1] = mfma16(a0, bf1, acc[0][1]);
    acc[1][0] = mfma16(a1, bf0, acc[1][0]);
    acc[1][1] = mfma16(a1, bf1, acc[1][1]);

    q0c = q0n; q1c = q1n;
  }

  // ---- epilogue
  const int col0 = cb + w * 32 + (lane & 15);
  const int r0 = q4 * 4;
  if constexpr (TOWS) {
    // plain stores to this k-chunk's private partial slab
    float* wsp = outp + kchunk * SLAB;
    #pragma unroll
    for (int mf = 0; mf < 2; ++mf) {
      #pragma unroll
      for (int i = 0; i < 4; ++i) {
        const int row = mf * 16 + r0 + i;
        wsp[row * OUT_F + col0]      = acc[mf][0][i];
        wsp[row * OUT_F + col0 + 16] = acc[mf][1][i];
      }
    }
  } else {
    // fallback: fp32 atomics onto bias-initialized out
    #pragma unroll
    for (int mf = 0; mf < 2; ++mf) {
      #pragma unroll
      for (int i = 0; i < 4; ++i) {
        const int row = mf * 16 + r0 + i;
        atomicAdd(outp + row * OUT_F + col0,      acc[mf][0][i]);
        atomicAdd(outp + row * OUT_F + col0 + 16, acc[mf][1][i]);
      }
    }
  }
}

extern "C" void kernel_launch(void* const* d_in, const int* in_sizes, int n_in,
                              void* d_out, int out_size, void* d_ws, size_t ws_size,
                              hipStream_t stream) {
  const float* x    = (const float*)d_in[0];
  const int*   qwp  = (const int*)d_in[1];
  const int*   qzp  = (const int*)d_in[2];
  const float* scp  = (const float*)d_in[3];
  const float* bias = (const float*)d_in[4];
  float* out = (float*)d_out;

  const size_t ws_part = (size_t)KSPLIT * SLAB * sizeof(float);   // 22.5 MB
  const size_t xb_sz   = (size_t)MROWS * IN_F * 2;                // 256 KB

  if (ws_size >= ws_part + xb_sz) {
    float* ws = (float*)d_ws;
    unsigned short* xb = (unsigned short*)((char*)d_ws + ws_part);
    xconv<<<128, 256, 0, stream>>>(x, xb);
    awq_main<true, true><<<NBLK, 256, 0, stream>>>(x, xb, qwp, qzp, scp, ws);
    awq_reduce<<<SLAB / 4 / 256, 256, 0, stream>>>(ws, bias, out);
  } else {
    awq_init<<<dim3(43, 32), 256, 0, stream>>>(bias, out);
    awq_main<false, false><<<NBLK, 256, 0, stream>>>(x, nullptr, qwp, qzp, scp, out);
  }
}